// Round 1
// baseline (1305.671 us; speedup 1.0000x reference)
//
#include <hip/hip_runtime.h>
#include <hip/hip_bf16.h>
#include <stdint.h>

#define TOK 4096   // B*S
#define HD  1024   // H
#define NE  8      // experts
#define ID  2688   // I
#define MAXK 6
#define AHID 50

#define BM 128
#define BN 128
#define BK 64

typedef float  f32x4  __attribute__((ext_vector_type(4)));
typedef __bf16 bf16x8 __attribute__((ext_vector_type(8)));
typedef ushort ushort8v __attribute__((ext_vector_type(8)));

__device__ __forceinline__ ushort f2bf(float f) {
  union { float f; uint32_t u; } v; v.f = f;
  return (ushort)((v.u + 0x7FFFu + ((v.u >> 16) & 1u)) >> 16);  // RNE
}

// global -> LDS direct load, 16B per lane. LDS dest must be wave-uniform.
#define GLD_LDS16(gp, lp)                                                      \
  __builtin_amdgcn_global_load_lds(                                            \
      (const __attribute__((address_space(1))) uint32_t*)(uintptr_t)(gp),      \
      (__attribute__((address_space(3))) uint32_t*)(uint32_t)(uintptr_t)(lp),  \
      16, 0, 0)

// ---------------- fp32 -> bf16 convert ----------------
__global__ void k_cvt(const float* __restrict__ src, ushort* __restrict__ dst, int n) {
  int idx = blockIdx.x * blockDim.x + threadIdx.x;
  int stride = gridDim.x * blockDim.x;
  for (int i = idx * 8; i < n; i += stride * 8) {
    float4 a = *(const float4*)(src + i);
    float4 b = *(const float4*)(src + i + 4);
    ushort8v o;
    o[0] = f2bf(a.x); o[1] = f2bf(a.y); o[2] = f2bf(a.z); o[3] = f2bf(a.w);
    o[4] = f2bf(b.x); o[5] = f2bf(b.y); o[6] = f2bf(b.z); o[7] = f2bf(b.w);
    *(ushort8v*)(dst + i) = o;
  }
}

// ---------------- router + actor + top-k scores ----------------
__global__ void k_router(const float* __restrict__ x,
                         const float* __restrict__ rw,
                         const float* __restrict__ aw1,
                         const float* __restrict__ ab1,
                         const float* __restrict__ aw2,
                         const float* __restrict__ ab2,
                         float* __restrict__ scores) {
  __shared__ float xs[HD];
  __shared__ float dots[64];
  const int t = blockIdx.x;
  const float* xp = x + (size_t)t * HD;
  for (int i = threadIdx.x; i < HD; i += 256) xs[i] = xp[i];
  __syncthreads();
  const int w = threadIdx.x >> 6, lane = threadIdx.x & 63;
  for (int r = w; r < NE + AHID; r += 4) {
    const float* row = (r < NE) ? (rw + (size_t)r * HD) : (aw1 + (size_t)(r - NE) * HD);
    float s = 0.f;
    for (int j = lane; j < HD; j += 64) s += xs[j] * row[j];
#pragma unroll
    for (int off = 32; off; off >>= 1) s += __shfl_down(s, off);
    if (lane == 0) dots[r] = s;
  }
  __syncthreads();
  if (threadIdx.x == 0) {
    // softmax over 8 experts
    float m = -1e30f;
    for (int e = 0; e < NE; ++e) m = fmaxf(m, dots[e]);
    float p[NE]; float sum = 0.f;
    for (int e = 0; e < NE; ++e) { p[e] = expf(dots[e] - m); sum += p[e]; }
    for (int e = 0; e < NE; ++e) p[e] /= sum;
    // actor: GELU(tanh approx) -> 6 logits -> clip -> argmax (first max)
    float logits[MAXK];
    for (int k = 0; k < MAXK; ++k) logits[k] = ab2[k];
    for (int i = 0; i < AHID; ++i) {
      float v = dots[NE + i] + ab1[i];
      float g = 0.5f * v * (1.f + tanhf(0.7978845608028654f * (v + 0.044715f * v * v * v)));
      for (int k = 0; k < MAXK; ++k) logits[k] += g * aw2[k * AHID + i];
    }
    int best = 0; float bv = fminf(fmaxf(logits[0], -30.f), 30.f);
    for (int k = 1; k < MAXK; ++k) {
      float lv = fminf(fmaxf(logits[k], -30.f), 30.f);
      if (lv > bv) { bv = lv; best = k; }
    }
    const int kk = best + 1;
    // stable descending rank; keep top-k scores
    float* so = scores + (size_t)t * NE;
    for (int e = 0; e < NE; ++e) {
      int rank = 0;
      for (int j = 0; j < NE; ++j)
        rank += (p[j] > p[e]) || (p[j] == p[e] && j < e);
      so[e] = (rank < kk) ? p[e] : 0.f;
    }
  }
}

// ---------------- fused gate+up GEMM -> silu(g)*u -> act (bf16) ----------------
// C = X[M,K] @ W[N,K]^T ; M=TOK, N=ID, K=HD
__global__ __launch_bounds__(256, 2) void k_gateup(
    const ushort* __restrict__ X,
    const ushort* __restrict__ Wg,
    const ushort* __restrict__ Wu,
    ushort* __restrict__ act) {
  __shared__ __attribute__((aligned(16))) ushort As[BM * BK];
  __shared__ __attribute__((aligned(16))) ushort Bg[BN * BK];
  __shared__ __attribute__((aligned(16))) ushort Bu[BN * BK];

  const int tn = blockIdx.x;          // 0..20
  const int tm = blockIdx.y;          // 0..31
  const int tid = threadIdx.x;
  const int lane = tid & 63;
  const int w = tid >> 6;
  const int wr = (w >> 1) * 64;
  const int wc = (w & 1) * 64;
  const int srow = lane >> 3;
  const int scol = (lane & 7) * 8;
  const int row0 = tm * BM, col0 = tn * BN;

  f32x4 accg[4][4] = {};
  f32x4 accu[4][4] = {};

  // per-lane global base pointers for staging (k advances by BK each step)
  const ushort* pa[4]; const ushort* pg[4]; const ushort* pu[4];
  ushort* la[4]; ushort* lg[4]; ushort* lu[4];
#pragma unroll
  for (int j = 0; j < 4; ++j) {
    const int c = w * 4 + j;
    const int r = c * 8 + srow;
    pa[j] = X  + (size_t)(row0 + r) * HD + scol;
    pg[j] = Wg + (size_t)(col0 + r) * HD + scol;
    pu[j] = Wu + (size_t)(col0 + r) * HD + scol;
    la[j] = &As[c * 512]; lg[j] = &Bg[c * 512]; lu[j] = &Bu[c * 512];
  }

  for (int kt = 0; kt < HD / BK; ++kt) {
    const int k0 = kt * BK;
    __syncthreads();
#pragma unroll
    for (int j = 0; j < 4; ++j) {
      GLD_LDS16(pa[j] + k0, la[j]);
      GLD_LDS16(pg[j] + k0, lg[j]);
      GLD_LDS16(pu[j] + k0, lu[j]);
    }
    __syncthreads();
#pragma unroll
    for (int kk = 0; kk < 2; ++kk) {
      const int kc = kk * 32 + (lane >> 4) * 8;
      const int rr = lane & 15;
      bf16x8 af[4], gf[4], uf[4];
#pragma unroll
      for (int m = 0; m < 4; ++m)
        af[m] = *(const bf16x8*)&As[(wr + m * 16 + rr) * BK + kc];
#pragma unroll
      for (int n = 0; n < 4; ++n) {
        gf[n] = *(const bf16x8*)&Bg[(wc + n * 16 + rr) * BK + kc];
        uf[n] = *(const bf16x8*)&Bu[(wc + n * 16 + rr) * BK + kc];
      }
#pragma unroll
      for (int m = 0; m < 4; ++m)
#pragma unroll
        for (int n = 0; n < 4; ++n) {
          accg[m][n] = __builtin_amdgcn_mfma_f32_16x16x32_bf16(af[m], gf[n], accg[m][n], 0, 0, 0);
          accu[m][n] = __builtin_amdgcn_mfma_f32_16x16x32_bf16(af[m], uf[n], accu[m][n], 0, 0, 0);
        }
    }
  }
  // epilogue: silu(g)*u -> bf16 act.  C/D map: col=lane&15, row=(lane>>4)*4+reg
  const int erow = (lane >> 4) * 4;
  const int ecol = lane & 15;
#pragma unroll
  for (int m = 0; m < 4; ++m) {
    const int gr = row0 + wr + m * 16 + erow;
#pragma unroll
    for (int n = 0; n < 4; ++n) {
      const int gc = col0 + wc + n * 16 + ecol;
#pragma unroll
      for (int j = 0; j < 4; ++j) {
        float g = accg[m][n][j];
        float u = accu[m][n][j];
        float h = (g / (1.f + __expf(-g))) * u;
        act[(size_t)(gr + j) * ID + gc] = f2bf(h);
      }
    }
  }
}

// ---------------- down GEMM + scaled accumulate into out ----------------
// out[t,h] (+)= score[t,e] * (act[M,K] @ W[N,K]^T) ; M=TOK, N=HD, K=ID
__global__ __launch_bounds__(256, 2) void k_down(
    const ushort* __restrict__ A,
    const ushort* __restrict__ W,
    const float* __restrict__ scores,
    const int e, const int init,
    float* __restrict__ out) {
  __shared__ __attribute__((aligned(16))) ushort As[BM * BK];
  __shared__ __attribute__((aligned(16))) ushort Bs[BN * BK];

  const int tn = blockIdx.x;          // 0..7
  const int tm = blockIdx.y;          // 0..31
  const int tid = threadIdx.x;
  const int lane = tid & 63;
  const int w = tid >> 6;
  const int wr = (w >> 1) * 64;
  const int wc = (w & 1) * 64;
  const int srow = lane >> 3;
  const int scol = (lane & 7) * 8;
  const int row0 = tm * BM, col0 = tn * BN;

  f32x4 acc[4][4] = {};

  const ushort* pa[4]; const ushort* pb[4];
  ushort* la[4]; ushort* lb[4];
#pragma unroll
  for (int j = 0; j < 4; ++j) {
    const int c = w * 4 + j;
    const int r = c * 8 + srow;
    pa[j] = A + (size_t)(row0 + r) * ID + scol;
    pb[j] = W + (size_t)(col0 + r) * ID + scol;
    la[j] = &As[c * 512]; lb[j] = &Bs[c * 512];
  }

  for (int kt = 0; kt < ID / BK; ++kt) {
    const int k0 = kt * BK;
    __syncthreads();
#pragma unroll
    for (int j = 0; j < 4; ++j) {
      GLD_LDS16(pa[j] + k0, la[j]);
      GLD_LDS16(pb[j] + k0, lb[j]);
    }
    __syncthreads();
#pragma unroll
    for (int kk = 0; kk < 2; ++kk) {
      const int kc = kk * 32 + (lane >> 4) * 8;
      const int rr = lane & 15;
      bf16x8 af[4], bf_[4];
#pragma unroll
      for (int m = 0; m < 4; ++m)
        af[m] = *(const bf16x8*)&As[(wr + m * 16 + rr) * BK + kc];
#pragma unroll
      for (int n = 0; n < 4; ++n)
        bf_[n] = *(const bf16x8*)&Bs[(wc + n * 16 + rr) * BK + kc];
#pragma unroll
      for (int m = 0; m < 4; ++m)
#pragma unroll
        for (int n = 0; n < 4; ++n)
          acc[m][n] = __builtin_amdgcn_mfma_f32_16x16x32_bf16(af[m], bf_[n], acc[m][n], 0, 0, 0);
    }
  }

  const int erow = (lane >> 4) * 4;
  const int ecol = lane & 15;
#pragma unroll
  for (int m = 0; m < 4; ++m) {
    const int gr = row0 + wr + m * 16 + erow;
    const float s0 = scores[(size_t)(gr + 0) * NE + e];
    const float s1 = scores[(size_t)(gr + 1) * NE + e];
    const float s2 = scores[(size_t)(gr + 2) * NE + e];
    const float s3 = scores[(size_t)(gr + 3) * NE + e];
#pragma unroll
    for (int n = 0; n < 4; ++n) {
      const int gc = col0 + wc + n * 16 + ecol;
      if (init) {
        out[(size_t)(gr + 0) * HD + gc] = s0 * acc[m][n][0];
        out[(size_t)(gr + 1) * HD + gc] = s1 * acc[m][n][1];
        out[(size_t)(gr + 2) * HD + gc] = s2 * acc[m][n][2];
        out[(size_t)(gr + 3) * HD + gc] = s3 * acc[m][n][3];
      } else {
        out[(size_t)(gr + 0) * HD + gc] += s0 * acc[m][n][0];
        out[(size_t)(gr + 1) * HD + gc] += s1 * acc[m][n][1];
        out[(size_t)(gr + 2) * HD + gc] += s2 * acc[m][n][2];
        out[(size_t)(gr + 3) * HD + gc] += s3 * acc[m][n][3];
      }
    }
  }
}

extern "C" void kernel_launch(void* const* d_in, const int* in_sizes, int n_in,
                              void* d_out, int out_size, void* d_ws, size_t ws_size,
                              hipStream_t stream) {
  const float* hs       = (const float*)d_in[0];
  const float* router_w = (const float*)d_in[1];
  const float* actor_w1 = (const float*)d_in[2];
  const float* actor_b1 = (const float*)d_in[3];
  const float* actor_w2 = (const float*)d_in[4];
  const float* actor_b2 = (const float*)d_in[5];
  const float* gate_w   = (const float*)d_in[6];
  const float* up_w     = (const float*)d_in[7];
  const float* down_w   = (const float*)d_in[8];
  float* out = (float*)d_out;

  const size_t sz_x   = (size_t)TOK * HD * 2;        // 8 MB
  const size_t sz_w   = (size_t)NE * ID * HD * 2;    // 44 MB each
  const size_t sz_act = (size_t)TOK * ID * 2;        // 22 MB
  const size_t sz_sc  = (size_t)TOK * NE * 4;        // 128 KB
  const size_t need = sz_x + 3 * sz_w + sz_act + sz_sc;
  if (ws_size < need) return;  // fail loudly via absmax (ws too small)

  char* ws = (char*)d_ws;
  ushort* Xb  = (ushort*)ws;
  ushort* Wgb = (ushort*)(ws + sz_x);
  ushort* Wub = (ushort*)(ws + sz_x + sz_w);
  ushort* Wdb = (ushort*)(ws + sz_x + 2 * sz_w);
  ushort* act = (ushort*)(ws + sz_x + 3 * sz_w);
  float*  scores = (float*)(ws + sz_x + 3 * sz_w + sz_act);

  k_cvt<<<1024, 256, 0, stream>>>(hs, Xb, TOK * HD);
  k_cvt<<<2048, 256, 0, stream>>>(gate_w, Wgb, NE * ID * HD);
  k_cvt<<<2048, 256, 0, stream>>>(up_w,   Wub, NE * ID * HD);
  k_cvt<<<2048, 256, 0, stream>>>(down_w, Wdb, NE * ID * HD);
  k_router<<<TOK, 256, 0, stream>>>(hs, router_w, actor_w1, actor_b1,
                                    actor_w2, actor_b2, scores);
  for (int e = 0; e < NE; ++e) {
    k_gateup<<<dim3(ID / BN, TOK / BM), 256, 0, stream>>>(
        Xb, Wgb + (size_t)e * ID * HD, Wub + (size_t)e * ID * HD, act);
    k_down<<<dim3(HD / BN, TOK / BM), 256, 0, stream>>>(
        act, Wdb + (size_t)e * HD * ID, scores, e, (e == 0) ? 1 : 0, out);
  }
}

// Round 2
// 882.967 us; speedup vs baseline: 1.4787x; 1.4787x over previous
//
#include <hip/hip_runtime.h>
#include <hip/hip_bf16.h>
#include <stdint.h>

#define TOK 4096   // B*S
#define HD  1024   // H
#define NE  8      // experts
#define ID  2688   // I
#define MAXK 6
#define AHID 50
#define NROW 58    // NE + AHID

#define BM 128
#define BN 128
#define BK 64

typedef float  f32x4  __attribute__((ext_vector_type(4)));
typedef __bf16 bf16x8 __attribute__((ext_vector_type(8)));
typedef ushort ushort8v __attribute__((ext_vector_type(8)));

__device__ __forceinline__ ushort f2bf(float f) {
  union { float f; uint32_t u; } v; v.f = f;
  return (ushort)((v.u + 0x7FFFu + ((v.u >> 16) & 1u)) >> 16);  // RNE
}

// global -> LDS direct load, 16B per lane. LDS dest must be wave-uniform.
#define GLD_LDS16(gp, lp)                                                      \
  __builtin_amdgcn_global_load_lds(                                            \
      (const __attribute__((address_space(1))) uint32_t*)(uintptr_t)(gp),      \
      (__attribute__((address_space(3))) uint32_t*)(uint32_t)(uintptr_t)(lp),  \
      16, 0, 0)

// ---------------- fp32 -> bf16 convert ----------------
__global__ void k_cvt(const float* __restrict__ src, ushort* __restrict__ dst, int n) {
  int idx = blockIdx.x * blockDim.x + threadIdx.x;
  int stride = gridDim.x * blockDim.x;
  for (int i = idx * 8; i < n; i += stride * 8) {
    float4 a = *(const float4*)(src + i);
    float4 b = *(const float4*)(src + i + 4);
    ushort8v o;
    o[0] = f2bf(a.x); o[1] = f2bf(a.y); o[2] = f2bf(a.z); o[3] = f2bf(a.w);
    o[4] = f2bf(b.x); o[5] = f2bf(b.y); o[6] = f2bf(b.z); o[7] = f2bf(b.w);
    *(ushort8v*)(dst + i) = o;
  }
}

// ---------------- router+actor logits: dots[r][t] = x[t] . w[r] (fp32) ------
// 4 tokens/block (one per wave); W chunk staged in LDS, shared by all waves.
__global__ __launch_bounds__(256) void k_logits(
    const float* __restrict__ x, const float* __restrict__ rw,
    const float* __restrict__ aw1, float* __restrict__ dots) {
  __shared__ float Wc[NROW * 64];
  const int tid = threadIdx.x, w = tid >> 6, lane = tid & 63;
  const int t = blockIdx.x * 4 + w;
  const float* xp = x + (size_t)t * HD;
  float acc[NROW];
#pragma unroll
  for (int r = 0; r < NROW; ++r) acc[r] = 0.f;
  for (int kc = 0; kc < HD; kc += 64) {
    __syncthreads();
    for (int i = tid; i < NROW * 64; i += 256) {
      int r = i >> 6, c = i & 63;
      Wc[i] = (r < NE) ? rw[(size_t)r * HD + kc + c]
                       : aw1[(size_t)(r - NE) * HD + kc + c];
    }
    __syncthreads();
    float xv = xp[kc + lane];
#pragma unroll
    for (int r = 0; r < NROW; ++r) acc[r] += xv * Wc[r * 64 + lane];
  }
#pragma unroll
  for (int r = 0; r < NROW; ++r) {
    float s = acc[r];
#pragma unroll
    for (int off = 32; off; off >>= 1) s += __shfl_down(s, off);
    if (lane == 0) dots[(size_t)r * TOK + t] = s;
  }
}

// ---------------- per-token: softmax, actor, top-k, expert lists ------------
__global__ __launch_bounds__(64) void k_select(
    const float* __restrict__ dots, const float* __restrict__ ab1_,
    const float* __restrict__ aw2_, const float* __restrict__ ab2_,
    float* __restrict__ scores, int* __restrict__ idx, int* __restrict__ cnt) {
  const int lane = threadIdx.x;
  const int t = blockIdx.x * 64 + lane;
  float d[NROW];
#pragma unroll
  for (int r = 0; r < NROW; ++r) d[r] = dots[(size_t)r * TOK + t];
  // softmax over 8 experts
  float m = d[0];
#pragma unroll
  for (int e = 1; e < NE; ++e) m = fmaxf(m, d[e]);
  float p[NE]; float sum = 0.f;
#pragma unroll
  for (int e = 0; e < NE; ++e) { p[e] = expf(d[e] - m); sum += p[e]; }
  float inv = 1.f / sum;
#pragma unroll
  for (int e = 0; e < NE; ++e) p[e] *= inv;
  // actor: GELU(tanh) -> 6 logits
  float lg[MAXK];
#pragma unroll
  for (int k = 0; k < MAXK; ++k) lg[k] = ab2_[k];
#pragma unroll
  for (int i = 0; i < AHID; ++i) {
    float v = d[NE + i] + ab1_[i];
    float g = 0.5f * v * (1.f + tanhf(0.7978845608028654f * (v + 0.044715f * v * v * v)));
#pragma unroll
    for (int k = 0; k < MAXK; ++k) lg[k] += g * aw2_[k * AHID + i];
  }
  int best = 0; float bv = fminf(fmaxf(lg[0], -30.f), 30.f);
#pragma unroll
  for (int k = 1; k < MAXK; ++k) {
    float lv = fminf(fmaxf(lg[k], -30.f), 30.f);
    if (lv > bv) { bv = lv; best = k; }
  }
  const int kk = best + 1;
  // stable descending rank; keep top-k scores
  float sc[NE];
#pragma unroll
  for (int e = 0; e < NE; ++e) {
    int rank = 0;
#pragma unroll
    for (int j = 0; j < NE; ++j)
      rank += (p[j] > p[e]) || (p[j] == p[e] && j < e);
    sc[e] = (rank < kk) ? p[e] : 0.f;
    scores[(size_t)t * NE + e] = sc[e];
  }
  // wave-aggregated append to per-expert index lists
#pragma unroll
  for (int e = 0; e < NE; ++e) {
    unsigned long long msk = __ballot(sc[e] > 0.f);
    int npop = __popcll(msk);
    int mypos = __popcll(msk & ((1ull << lane) - 1ull));
    int base = 0;
    if (lane == 0 && npop) base = atomicAdd(cnt + e, npop);
    base = __shfl(base, 0);
    if (sc[e] > 0.f) idx[e * TOK + base + mypos] = t;
  }
}

// ---------------- fused gate+up GEMM (gathered rows) -> silu(g)*u -> act ----
__global__ __launch_bounds__(256, 2) void k_gateup(
    const ushort* __restrict__ X, const int* __restrict__ idx,
    const int* __restrict__ cntp,
    const ushort* __restrict__ Wg, const ushort* __restrict__ Wu,
    ushort* __restrict__ act) {
  __shared__ __attribute__((aligned(16))) ushort As[BM * BK];
  __shared__ __attribute__((aligned(16))) ushort Bg[BN * BK];
  __shared__ __attribute__((aligned(16))) ushort Bu[BN * BK];

  const int n = *cntp;
  const int tm = blockIdx.y;
  const int row0 = tm * BM;
  if (row0 >= n) return;
  const int tn = blockIdx.x;
  const int tid = threadIdx.x;
  const int lane = tid & 63;
  const int w = tid >> 6;
  const int wr = (w >> 1) * 64;
  const int wc = (w & 1) * 64;
  const int srow = lane >> 3;
  const int scol = (lane & 7) * 8;
  const int col0 = tn * BN;

  f32x4 accg[4][4] = {};
  f32x4 accu[4][4] = {};

  const ushort* pa[4]; const ushort* pg[4]; const ushort* pu[4];
  ushort* la[4]; ushort* lg[4]; ushort* lu[4];
#pragma unroll
  for (int j = 0; j < 4; ++j) {
    const int c = w * 4 + j;
    const int r = c * 8 + srow;
    const int token = idx[min(row0 + r, n - 1)];
    pa[j] = X  + (size_t)token * HD + scol;
    pg[j] = Wg + (size_t)(col0 + r) * HD + scol;
    pu[j] = Wu + (size_t)(col0 + r) * HD + scol;
    la[j] = &As[c * 512]; lg[j] = &Bg[c * 512]; lu[j] = &Bu[c * 512];
  }

  for (int kt = 0; kt < HD / BK; ++kt) {
    const int k0 = kt * BK;
    __syncthreads();
#pragma unroll
    for (int j = 0; j < 4; ++j) {
      GLD_LDS16(pa[j] + k0, la[j]);
      GLD_LDS16(pg[j] + k0, lg[j]);
      GLD_LDS16(pu[j] + k0, lu[j]);
    }
    __syncthreads();
#pragma unroll
    for (int kk = 0; kk < 2; ++kk) {
      const int kc = kk * 32 + (lane >> 4) * 8;
      const int rr = lane & 15;
      bf16x8 af[4], gf[4], uf[4];
#pragma unroll
      for (int m = 0; m < 4; ++m)
        af[m] = *(const bf16x8*)&As[(wr + m * 16 + rr) * BK + kc];
#pragma unroll
      for (int nn = 0; nn < 4; ++nn) {
        gf[nn] = *(const bf16x8*)&Bg[(wc + nn * 16 + rr) * BK + kc];
        uf[nn] = *(const bf16x8*)&Bu[(wc + nn * 16 + rr) * BK + kc];
      }
#pragma unroll
      for (int m = 0; m < 4; ++m)
#pragma unroll
        for (int nn = 0; nn < 4; ++nn) {
          accg[m][nn] = __builtin_amdgcn_mfma_f32_16x16x32_bf16(af[m], gf[nn], accg[m][nn], 0, 0, 0);
          accu[m][nn] = __builtin_amdgcn_mfma_f32_16x16x32_bf16(af[m], uf[nn], accu[m][nn], 0, 0, 0);
        }
    }
  }
  const int erow = (lane >> 4) * 4;
  const int ecol = lane & 15;
#pragma unroll
  for (int m = 0; m < 4; ++m) {
    const int gr = row0 + wr + m * 16 + erow;   // compact row
#pragma unroll
    for (int nn = 0; nn < 4; ++nn) {
      const int gc = col0 + wc + nn * 16 + ecol;
#pragma unroll
      for (int j = 0; j < 4; ++j) {
        float g = accg[m][nn][j];
        float u = accu[m][nn][j];
        float h = (g / (1.f + __expf(-g))) * u;
        act[(size_t)(gr + j) * ID + gc] = f2bf(h);
      }
    }
  }
}

// ---------------- down GEMM (compact) + scatter score*y into out -----------
// 64x64 tile, 4 waves of 32x32 -> ~448 blocks at avg count (latency hiding)
__global__ __launch_bounds__(256) void k_down(
    const ushort* __restrict__ A, const ushort* __restrict__ W,
    const float* __restrict__ scores, const int* __restrict__ idx,
    const int* __restrict__ cntp, const int e, float* __restrict__ out) {
  __shared__ __attribute__((aligned(16))) ushort As[64 * 64];
  __shared__ __attribute__((aligned(16))) ushort Bs[64 * 64];

  const int n = *cntp;
  const int tm = blockIdx.y;
  const int row0 = tm * 64;
  if (row0 >= n) return;
  const int tn = blockIdx.x;
  const int col0 = tn * 64;
  const int tid = threadIdx.x, lane = tid & 63, w = tid >> 6;
  const int wr = (w >> 1) * 32, wc = (w & 1) * 32;
  const int srow = lane >> 3, scol = (lane & 7) * 8;

  f32x4 acc[2][2] = {};
  const ushort* pa[2]; const ushort* pb[2];
  ushort* la[2]; ushort* lb[2];
#pragma unroll
  for (int j = 0; j < 2; ++j) {
    const int c = w * 2 + j;       // 0..7
    const int r = c * 8 + srow;    // 0..63
    pa[j] = A + (size_t)min(row0 + r, n - 1) * ID + scol;
    pb[j] = W + (size_t)(col0 + r) * ID + scol;
    la[j] = &As[c * 512]; lb[j] = &Bs[c * 512];
  }

  for (int kt = 0; kt < ID / 64; ++kt) {
    const int k0 = kt * 64;
    __syncthreads();
#pragma unroll
    for (int j = 0; j < 2; ++j) {
      GLD_LDS16(pa[j] + k0, la[j]);
      GLD_LDS16(pb[j] + k0, lb[j]);
    }
    __syncthreads();
#pragma unroll
    for (int kk = 0; kk < 2; ++kk) {
      const int kc = kk * 32 + (lane >> 4) * 8;
      const int rr = lane & 15;
      bf16x8 af[2], bf_[2];
#pragma unroll
      for (int m = 0; m < 2; ++m)
        af[m] = *(const bf16x8*)&As[(wr + m * 16 + rr) * 64 + kc];
#pragma unroll
      for (int nn = 0; nn < 2; ++nn)
        bf_[nn] = *(const bf16x8*)&Bs[(wc + nn * 16 + rr) * 64 + kc];
#pragma unroll
      for (int m = 0; m < 2; ++m)
#pragma unroll
        for (int nn = 0; nn < 2; ++nn)
          acc[m][nn] = __builtin_amdgcn_mfma_f32_16x16x32_bf16(af[m], bf_[nn], acc[m][nn], 0, 0, 0);
    }
  }

  const int erow = (lane >> 4) * 4, ecol = lane & 15;
#pragma unroll
  for (int m = 0; m < 2; ++m) {
    const int cr0 = row0 + wr + m * 16 + erow;
#pragma unroll
    for (int j = 0; j < 4; ++j) {
      const int cr = cr0 + j;
      if (cr < n) {
        const int token = idx[cr];
        const float s = scores[(size_t)token * NE + e];
        float* op = out + (size_t)token * HD + col0 + wc;
#pragma unroll
        for (int nn = 0; nn < 2; ++nn)
          op[nn * 16 + ecol] += s * acc[m][nn][j];
      }
    }
  }
}

extern "C" void kernel_launch(void* const* d_in, const int* in_sizes, int n_in,
                              void* d_out, int out_size, void* d_ws, size_t ws_size,
                              hipStream_t stream) {
  const float* hs       = (const float*)d_in[0];
  const float* router_w = (const float*)d_in[1];
  const float* actor_w1 = (const float*)d_in[2];
  const float* actor_b1 = (const float*)d_in[3];
  const float* actor_w2 = (const float*)d_in[4];
  const float* actor_b2 = (const float*)d_in[5];
  const float* gate_w   = (const float*)d_in[6];
  const float* up_w     = (const float*)d_in[7];
  const float* down_w   = (const float*)d_in[8];
  float* out = (float*)d_out;

  const size_t sz_x   = (size_t)TOK * HD * 2;        // 8 MB
  const size_t sz_w   = (size_t)NE * ID * HD * 2;    // 44 MB each
  const size_t sz_act = (size_t)TOK * ID * 2;        // 22 MB
  const size_t sz_sc  = (size_t)TOK * NE * 4;        // 128 KB
  const size_t sz_dt  = (size_t)64 * TOK * 4;        // 1 MB
  const size_t sz_ix  = (size_t)NE * TOK * 4;        // 128 KB
  const size_t need = sz_x + 3 * sz_w + sz_act + sz_sc + sz_dt + sz_ix + 64;
  if (ws_size < need) return;

  char* ws = (char*)d_ws;
  ushort* Xb  = (ushort*)ws;
  ushort* Wgb = (ushort*)(ws + sz_x);
  ushort* Wub = (ushort*)(ws + sz_x + sz_w);
  ushort* Wdb = (ushort*)(ws + sz_x + 2 * sz_w);
  ushort* act = (ushort*)(ws + sz_x + 3 * sz_w);
  float*  scores = (float*)(ws + sz_x + 3 * sz_w + sz_act);
  float*  dots   = (float*)(ws + sz_x + 3 * sz_w + sz_act + sz_sc);
  int*    idx    = (int*)  (ws + sz_x + 3 * sz_w + sz_act + sz_sc + sz_dt);
  int*    cnt    = (int*)  (ws + sz_x + 3 * sz_w + sz_act + sz_sc + sz_dt + sz_ix);

  hipMemsetAsync(out, 0, (size_t)TOK * HD * 4, stream);
  hipMemsetAsync(cnt, 0, NE * 4, stream);

  k_cvt<<<1024, 256, 0, stream>>>(hs, Xb, TOK * HD);
  k_cvt<<<2048, 256, 0, stream>>>(gate_w, Wgb, NE * ID * HD);
  k_cvt<<<2048, 256, 0, stream>>>(up_w,   Wub, NE * ID * HD);
  k_cvt<<<2048, 256, 0, stream>>>(down_w, Wdb, NE * ID * HD);

  k_logits<<<TOK / 4, 256, 0, stream>>>(hs, router_w, actor_w1, dots);
  k_select<<<TOK / 64, 64, 0, stream>>>(dots, actor_b1, actor_w2, actor_b2,
                                        scores, idx, cnt);

  for (int e = 0; e < NE; ++e) {
    k_gateup<<<dim3(ID / BN, TOK / BM), 256, 0, stream>>>(
        Xb, idx + e * TOK, cnt + e,
        Wgb + (size_t)e * ID * HD, Wub + (size_t)e * ID * HD, act);
    k_down<<<dim3(HD / 64, TOK / 64), 256, 0, stream>>>(
        act, Wdb + (size_t)e * HD * ID, scores, idx + e * TOK, cnt + e, e, out);
  }
}

// Round 3
// 797.120 us; speedup vs baseline: 1.6380x; 1.1077x over previous
//
#include <hip/hip_runtime.h>
#include <hip/hip_bf16.h>
#include <stdint.h>

#define TOK 4096   // B*S
#define HD  1024   // H
#define NE  8      // experts
#define ID  2688   // I
#define MAXK 6
#define AHID 50
#define NROW 58    // NE + AHID
#define KCH 64     // logits split-K chunk
#define NCH (HD / KCH)  // 16

#define BM 128
#define BN 128
#define BK 64

typedef float  f32x4  __attribute__((ext_vector_type(4)));
typedef __bf16 bf16x8 __attribute__((ext_vector_type(8)));
typedef ushort ushort8v __attribute__((ext_vector_type(8)));

__device__ __forceinline__ ushort f2bf(float f) {
  union { float f; uint32_t u; } v; v.f = f;
  return (ushort)((v.u + 0x7FFFu + ((v.u >> 16) & 1u)) >> 16);  // RNE
}

// global -> LDS direct load, 16B per lane. LDS dest must be wave-uniform.
#define GLD_LDS16(gp, lp)                                                      \
  __builtin_amdgcn_global_load_lds(                                            \
      (const __attribute__((address_space(1))) uint32_t*)(uintptr_t)(gp),      \
      (__attribute__((address_space(3))) uint32_t*)(uint32_t)(uintptr_t)(lp),  \
      16, 0, 0)

// ---------------- fp32 -> bf16 convert (weights) ----------------
__global__ void k_cvt(const float* __restrict__ src, ushort* __restrict__ dst, int n) {
  int idx = blockIdx.x * blockDim.x + threadIdx.x;
  int stride = gridDim.x * blockDim.x;
  for (int i = idx * 8; i < n; i += stride * 8) {
    float4 a = *(const float4*)(src + i);
    float4 b = *(const float4*)(src + i + 4);
    ushort8v o;
    o[0] = f2bf(a.x); o[1] = f2bf(a.y); o[2] = f2bf(a.z); o[3] = f2bf(a.w);
    o[4] = f2bf(b.x); o[5] = f2bf(b.y); o[6] = f2bf(b.z); o[7] = f2bf(b.w);
    *(ushort8v*)(dst + i) = o;
  }
}

// ---------------- logits split-K: partial[c][r][t] = x[t,kc].w[r,kc] --------
// One thread per token; W via wave-uniform scalar loads (SGPR FMA operand).
// Side product: Xb (bf16 x) for the MFMA GEMMs.
__global__ __launch_bounds__(256) void k_logits(
    const float* __restrict__ x, const float* __restrict__ rw,
    const float* __restrict__ aw1, float* __restrict__ partial,
    ushort* __restrict__ Xb) {
  const int t = blockIdx.x * 256 + threadIdx.x;
  const int c = blockIdx.y;
  const int k0 = c * KCH;
  const float* xp = x + (size_t)t * HD + k0;
  ushort* xbp = Xb + (size_t)t * HD + k0;
  float acc[NROW];
#pragma unroll
  for (int r = 0; r < NROW; ++r) acc[r] = 0.f;
  for (int i = 0; i < KCH / 4; ++i) {   // rolled: keeps icache small
    float4 xv = *(const float4*)(xp + 4 * i);
    ushort4 o;
    o.x = f2bf(xv.x); o.y = f2bf(xv.y); o.z = f2bf(xv.z); o.w = f2bf(xv.w);
    *(ushort4*)(xbp + 4 * i) = o;
#pragma unroll
    for (int r = 0; r < NROW; ++r) {
      const float* wp = ((r < NE) ? (rw + (size_t)r * HD)
                                  : (aw1 + (size_t)(r - NE) * HD)) + k0 + 4 * i;
      acc[r] += xv.x * wp[0] + xv.y * wp[1] + xv.z * wp[2] + xv.w * wp[3];
    }
  }
#pragma unroll
  for (int r = 0; r < NROW; ++r)
    partial[((size_t)c * NROW + r) * TOK + t] = acc[r];
}

// ---------------- fixed-order chunk reduction: dots[r][t] -------------------
__global__ __launch_bounds__(256) void k_reduce(
    const float* __restrict__ partial, float* __restrict__ dots) {
  const int t = blockIdx.x * 256 + threadIdx.x;
  const int r = blockIdx.y;
  float s = 0.f;
#pragma unroll
  for (int c = 0; c < NCH; ++c)
    s += partial[((size_t)c * NROW + r) * TOK + t];
  dots[(size_t)r * TOK + t] = s;
}

// ---------------- per-token: softmax, actor, top-k, expert lists ------------
__global__ __launch_bounds__(64) void k_select(
    const float* __restrict__ dots, const float* __restrict__ ab1_,
    const float* __restrict__ aw2_, const float* __restrict__ ab2_,
    float* __restrict__ scores, int* __restrict__ idx, int* __restrict__ cnt) {
  const int lane = threadIdx.x;
  const int t = blockIdx.x * 64 + lane;
  float d[NROW];
#pragma unroll
  for (int r = 0; r < NROW; ++r) d[r] = dots[(size_t)r * TOK + t];
  float m = d[0];
#pragma unroll
  for (int e = 1; e < NE; ++e) m = fmaxf(m, d[e]);
  float p[NE]; float sum = 0.f;
#pragma unroll
  for (int e = 0; e < NE; ++e) { p[e] = expf(d[e] - m); sum += p[e]; }
  float inv = 1.f / sum;
#pragma unroll
  for (int e = 0; e < NE; ++e) p[e] *= inv;
  float lg[MAXK];
#pragma unroll
  for (int k = 0; k < MAXK; ++k) lg[k] = ab2_[k];
#pragma unroll
  for (int i = 0; i < AHID; ++i) {
    float v = d[NE + i] + ab1_[i];
    float g = 0.5f * v * (1.f + tanhf(0.7978845608028654f * (v + 0.044715f * v * v * v)));
#pragma unroll
    for (int k = 0; k < MAXK; ++k) lg[k] += g * aw2_[k * AHID + i];
  }
  int best = 0; float bv = fminf(fmaxf(lg[0], -30.f), 30.f);
#pragma unroll
  for (int k = 1; k < MAXK; ++k) {
    float lv = fminf(fmaxf(lg[k], -30.f), 30.f);
    if (lv > bv) { bv = lv; best = k; }
  }
  const int kk = best + 1;
  float sc[NE];
#pragma unroll
  for (int e = 0; e < NE; ++e) {
    int rank = 0;
#pragma unroll
    for (int j = 0; j < NE; ++j)
      rank += (p[j] > p[e]) || (p[j] == p[e] && j < e);
    sc[e] = (rank < kk) ? p[e] : 0.f;
    scores[(size_t)t * NE + e] = sc[e];
  }
#pragma unroll
  for (int e = 0; e < NE; ++e) {
    unsigned long long msk = __ballot(sc[e] > 0.f);
    int npop = __popcll(msk);
    int mypos = __popcll(msk & ((1ull << lane) - 1ull));
    int base = 0;
    if (lane == 0 && npop) base = atomicAdd(cnt + e, npop);
    base = __shfl(base, 0);
    if (sc[e] > 0.f) idx[e * TOK + base + mypos] = t;
  }
}

// ---------------- grouped gate+up GEMM -> silu(g)*u -> act ------------------
// e = e0 + blockIdx.z ; act region = act + e*actStrideRows*ID
__global__ __launch_bounds__(256, 2) void k_gateup(
    const ushort* __restrict__ X, const int* __restrict__ idx,
    const int* __restrict__ cnt,
    const ushort* __restrict__ Wg, const ushort* __restrict__ Wu,
    ushort* __restrict__ act, const int e0, const int actStrideRows) {
  __shared__ __attribute__((aligned(16))) ushort As[BM * BK];
  __shared__ __attribute__((aligned(16))) ushort Bg[BN * BK];
  __shared__ __attribute__((aligned(16))) ushort Bu[BN * BK];

  const int e = e0 + blockIdx.z;
  const int n = cnt[e];
  const int row0 = blockIdx.y * BM;
  if (row0 >= n) return;
  const int* idx_e = idx + e * TOK;
  const ushort* WgE = Wg + (size_t)e * ID * HD;
  const ushort* WuE = Wu + (size_t)e * ID * HD;
  ushort* actE = act + (size_t)actStrideRows * e * ID;

  const int tid = threadIdx.x;
  const int lane = tid & 63;
  const int w = tid >> 6;
  const int wr = (w >> 1) * 64;
  const int wc = (w & 1) * 64;
  const int srow = lane >> 3;
  const int scol = (lane & 7) * 8;
  const int col0 = blockIdx.x * BN;

  f32x4 accg[4][4] = {};
  f32x4 accu[4][4] = {};

  const ushort* pa[4]; const ushort* pg[4]; const ushort* pu[4];
  ushort* la[4]; ushort* lg[4]; ushort* lu[4];
#pragma unroll
  for (int j = 0; j < 4; ++j) {
    const int cc = w * 4 + j;
    const int r = cc * 8 + srow;
    const int token = idx_e[min(row0 + r, n - 1)];
    pa[j] = X   + (size_t)token * HD + scol;
    pg[j] = WgE + (size_t)(col0 + r) * HD + scol;
    pu[j] = WuE + (size_t)(col0 + r) * HD + scol;
    la[j] = &As[cc * 512]; lg[j] = &Bg[cc * 512]; lu[j] = &Bu[cc * 512];
  }

  for (int kt = 0; kt < HD / BK; ++kt) {
    const int k0 = kt * BK;
    __syncthreads();
#pragma unroll
    for (int j = 0; j < 4; ++j) {
      GLD_LDS16(pa[j] + k0, la[j]);
      GLD_LDS16(pg[j] + k0, lg[j]);
      GLD_LDS16(pu[j] + k0, lu[j]);
    }
    __syncthreads();
#pragma unroll
    for (int kk = 0; kk < 2; ++kk) {
      const int kc = kk * 32 + (lane >> 4) * 8;
      const int rr = lane & 15;
      bf16x8 af[4], gf[4], uf[4];
#pragma unroll
      for (int m = 0; m < 4; ++m)
        af[m] = *(const bf16x8*)&As[(wr + m * 16 + rr) * BK + kc];
#pragma unroll
      for (int nn = 0; nn < 4; ++nn) {
        gf[nn] = *(const bf16x8*)&Bg[(wc + nn * 16 + rr) * BK + kc];
        uf[nn] = *(const bf16x8*)&Bu[(wc + nn * 16 + rr) * BK + kc];
      }
#pragma unroll
      for (int m = 0; m < 4; ++m)
#pragma unroll
        for (int nn = 0; nn < 4; ++nn) {
          accg[m][nn] = __builtin_amdgcn_mfma_f32_16x16x32_bf16(af[m], gf[nn], accg[m][nn], 0, 0, 0);
          accu[m][nn] = __builtin_amdgcn_mfma_f32_16x16x32_bf16(af[m], uf[nn], accu[m][nn], 0, 0, 0);
        }
    }
  }
  const int erow = (lane >> 4) * 4;
  const int ecol = lane & 15;
#pragma unroll
  for (int m = 0; m < 4; ++m) {
    const int gr = row0 + wr + m * 16 + erow;
#pragma unroll
    for (int nn = 0; nn < 4; ++nn) {
      const int gc = col0 + wc + nn * 16 + ecol;
#pragma unroll
      for (int j = 0; j < 4; ++j) {
        float g = accg[m][nn][j];
        float u = accu[m][nn][j];
        float h = (g / (1.f + __expf(-g))) * u;
        actE[(size_t)(gr + j) * ID + gc] = f2bf(h);
      }
    }
  }
}

// ---------------- down GEMM (compact, per-expert) + scatter score*y ---------
__global__ __launch_bounds__(256) void k_down(
    const ushort* __restrict__ act, const ushort* __restrict__ Wd,
    const float* __restrict__ scores, const int* __restrict__ idx,
    const int* __restrict__ cnt, const int e, const int actStrideRows,
    float* __restrict__ out) {
  __shared__ __attribute__((aligned(16))) ushort As[64 * 64];
  __shared__ __attribute__((aligned(16))) ushort Bs[64 * 64];

  const int n = cnt[e];
  const int row0 = blockIdx.y * 64;
  if (row0 >= n) return;
  const int* idx_e = idx + e * TOK;
  const ushort* A = act + (size_t)actStrideRows * e * ID;
  const ushort* W = Wd + (size_t)e * HD * ID;
  const int col0 = blockIdx.x * 64;
  const int tid = threadIdx.x, lane = tid & 63, w = tid >> 6;
  const int wr = (w >> 1) * 32, wc = (w & 1) * 32;
  const int srow = lane >> 3, scol = (lane & 7) * 8;

  f32x4 acc[2][2] = {};
  const ushort* pa[2]; const ushort* pb[2];
  ushort* la[2]; ushort* lb[2];
#pragma unroll
  for (int j = 0; j < 2; ++j) {
    const int cc = w * 2 + j;
    const int r = cc * 8 + srow;
    pa[j] = A + (size_t)min(row0 + r, n - 1) * ID + scol;
    pb[j] = W + (size_t)(col0 + r) * ID + scol;
    la[j] = &As[cc * 512]; lb[j] = &Bs[cc * 512];
  }

  for (int kt = 0; kt < ID / 64; ++kt) {
    const int k0 = kt * 64;
    __syncthreads();
#pragma unroll
    for (int j = 0; j < 2; ++j) {
      GLD_LDS16(pa[j] + k0, la[j]);
      GLD_LDS16(pb[j] + k0, lb[j]);
    }
    __syncthreads();
#pragma unroll
    for (int kk = 0; kk < 2; ++kk) {
      const int kc = kk * 32 + (lane >> 4) * 8;
      const int rr = lane & 15;
      bf16x8 af[2], bf_[2];
#pragma unroll
      for (int m = 0; m < 2; ++m)
        af[m] = *(const bf16x8*)&As[(wr + m * 16 + rr) * 64 + kc];
#pragma unroll
      for (int nn = 0; nn < 2; ++nn)
        bf_[nn] = *(const bf16x8*)&Bs[(wc + nn * 16 + rr) * 64 + kc];
#pragma unroll
      for (int m = 0; m < 2; ++m)
#pragma unroll
        for (int nn = 0; nn < 2; ++nn)
          acc[m][nn] = __builtin_amdgcn_mfma_f32_16x16x32_bf16(af[m], bf_[nn], acc[m][nn], 0, 0, 0);
    }
  }

  const int erow = (lane >> 4) * 4, ecol = lane & 15;
#pragma unroll
  for (int m = 0; m < 2; ++m) {
    const int cr0 = row0 + wr + m * 16 + erow;
#pragma unroll
    for (int j = 0; j < 4; ++j) {
      const int cr = cr0 + j;
      if (cr < n) {
        const int token = idx_e[cr];
        const float s = scores[(size_t)token * NE + e];
        float* op = out + (size_t)token * HD + col0 + wc;
#pragma unroll
        for (int nn = 0; nn < 2; ++nn)
          op[nn * 16 + ecol] += s * acc[m][nn][j];
      }
    }
  }
}

extern "C" void kernel_launch(void* const* d_in, const int* in_sizes, int n_in,
                              void* d_out, int out_size, void* d_ws, size_t ws_size,
                              hipStream_t stream) {
  const float* hs       = (const float*)d_in[0];
  const float* router_w = (const float*)d_in[1];
  const float* actor_w1 = (const float*)d_in[2];
  const float* actor_b1 = (const float*)d_in[3];
  const float* actor_w2 = (const float*)d_in[4];
  const float* actor_b2 = (const float*)d_in[5];
  const float* gate_w   = (const float*)d_in[6];
  const float* up_w     = (const float*)d_in[7];
  const float* down_w   = (const float*)d_in[8];
  float* out = (float*)d_out;

  const size_t sz_x    = (size_t)TOK * HD * 2;              // 8 MB
  const size_t sz_w    = (size_t)NE * ID * HD * 2;          // 44 MB each
  const size_t sz_act1 = (size_t)TOK * ID * 2;              // 22 MB (shared)
  const size_t sz_actC = (size_t)NE * TOK * ID * 2;         // 176 MB (per-expert)
  const size_t sz_part = (size_t)NCH * NROW * TOK * 4;      // 15.2 MB (aliases act)
  const size_t sz_dt   = (size_t)NROW * TOK * 4;            // 0.95 MB
  const size_t sz_sc   = (size_t)TOK * NE * 4;
  const size_t sz_ix   = (size_t)NE * TOK * 4;

  const size_t fixed   = sz_x + 3 * sz_w;
  const size_t tail    = sz_dt + sz_sc + sz_ix + 256;
  const size_t need_fb = fixed + (sz_act1 > sz_part ? sz_act1 : sz_part) + tail;
  const size_t need_cb = fixed + sz_actC + tail;
  if (ws_size < need_fb) return;
  const bool combined = (ws_size >= need_cb);
  const size_t act_sz = combined ? sz_actC : (sz_act1 > sz_part ? sz_act1 : sz_part);

  char* ws = (char*)d_ws;
  ushort* Xb  = (ushort*)ws;
  ushort* Wgb = (ushort*)(ws + sz_x);
  ushort* Wub = (ushort*)(ws + sz_x + sz_w);
  ushort* Wdb = (ushort*)(ws + sz_x + 2 * sz_w);
  ushort* act = (ushort*)(ws + fixed);
  float*  partial = (float*)(ws + fixed);                   // aliases act (consumed first)
  float*  dots   = (float*)(ws + fixed + act_sz);
  float*  scores = (float*)(ws + fixed + act_sz + sz_dt);
  int*    idx    = (int*)  (ws + fixed + act_sz + sz_dt + sz_sc);
  int*    cnt    = (int*)  (ws + fixed + act_sz + sz_dt + sz_sc + sz_ix);

  hipMemsetAsync(out, 0, (size_t)TOK * HD * 4, stream);
  hipMemsetAsync(cnt, 0, NE * 4, stream);

  k_cvt<<<2048, 256, 0, stream>>>(gate_w, Wgb, NE * ID * HD);
  k_cvt<<<2048, 256, 0, stream>>>(up_w,   Wub, NE * ID * HD);
  k_cvt<<<2048, 256, 0, stream>>>(down_w, Wdb, NE * ID * HD);

  k_logits<<<dim3(TOK / 256, NCH), 256, 0, stream>>>(hs, router_w, actor_w1, partial, Xb);
  k_reduce<<<dim3(TOK / 256, NROW), 256, 0, stream>>>(partial, dots);
  k_select<<<TOK / 64, 64, 0, stream>>>(dots, actor_b1, actor_w2, actor_b2,
                                        scores, idx, cnt);

  if (combined) {
    k_gateup<<<dim3(ID / BN, TOK / BM, NE), 256, 0, stream>>>(
        Xb, idx, cnt, Wgb, Wub, act, 0, TOK);
    for (int e = 0; e < NE; ++e)
      k_down<<<dim3(HD / 64, TOK / 64), 256, 0, stream>>>(
          act, Wdb, scores, idx, cnt, e, TOK, out);
  } else {
    for (int e = 0; e < NE; ++e) {
      k_gateup<<<dim3(ID / BN, TOK / BM, 1), 256, 0, stream>>>(
          Xb, idx, cnt, Wgb, Wub, act, e, 0);
      k_down<<<dim3(HD / 64, TOK / 64), 256, 0, stream>>>(
          act, Wdb, scores, idx, cnt, e, 0, out);
    }
  }
}